// Round 10
// baseline (134.041 us; speedup 1.0000x reference)
//
#include <hip/hip_runtime.h>
#include <hip/hip_cooperative_groups.h>
#include <stdint.h>

namespace cg = cooperative_groups;

#define NN 8192
#define NE 8192
#define DIM 256
#define NW 128   // 64-bit words per adjacency row (8192 bits)
#define HCAP 64  // max common neighbors; worst case i==j -> deg_max ~55
#define TE 32    // edges per block
#define NBLK 256 // cooperative grid: 1 block/CU, 16 waves/CU

typedef short bf16x8 __attribute__((ext_vector_type(8)));
typedef float f32x4 __attribute__((ext_vector_type(4)));

__device__ __forceinline__ unsigned short f2bf(float f) {
  uint32_t u = __builtin_bit_cast(uint32_t, f);
  u += 0x7fffu + ((u >> 16) & 1u);   // round-to-nearest-even
  return (unsigned short)(u >> 16);
}
__device__ __forceinline__ float bf2f(unsigned short h) {
  uint32_t u = ((uint32_t)h) << 16;
  return __builtin_bit_cast(float, u);
}

#define LDP 264  // 256 + 8 bf16 pad (row stride 528 B, 2-way bank alias = free)

__device__ __forceinline__ void load_w16(const unsigned short* __restrict__ Wt,
                                         bf16x8 w[8], int lane, int wave) {
  const int lr = lane & 15;
  const int kl = (lane >> 4) * 8;
  const int n0 = wave * 16;
#pragma unroll
  for (int kk = 0; kk < 8; ++kk)
    w[kk] = *(const bf16x8*)(Wt + (size_t)(n0 + lr) * DIM + kk * 32 + kl);
}

__device__ __forceinline__ void gemm16(const unsigned short (*src)[LDP],
                                       const bf16x8 w[8],
                                       f32x4 acc[2], int lane) {
  const int lr = lane & 15;
  const int kl = (lane >> 4) * 8;
#pragma unroll
  for (int kk = 0; kk < 8; ++kk) {
    const int k0 = kk * 32 + kl;
    bf16x8 a0 = *(const bf16x8*)(&src[lr][k0]);
    bf16x8 a1 = *(const bf16x8*)(&src[16 + lr][k0]);
    acc[0] = __builtin_amdgcn_mfma_f32_16x16x32_bf16(a0, w[kk], acc[0], 0, 0, 0);
    acc[1] = __builtin_amdgcn_mfma_f32_16x16x32_bf16(a1, w[kk], acc[1], 0, 0, 0);
  }
}

__device__ __forceinline__ void epilogue16(f32x4 acc[2], float bb, bool relu,
                                           unsigned short (*dst)[LDP],
                                           int lane, int wave) {
  const int lc = lane & 15;
  const int rg = (lane >> 4) * 4;
  const int col = wave * 16 + lc;
#pragma unroll
  for (int m = 0; m < 2; ++m)
#pragma unroll
    for (int q = 0; q < 4; ++q) {
      float v = acc[m][q] + bb;
      if (relu) v = fmaxf(v, 0.f);
      dst[m * 16 + rg + q][col] = f2bf(v);
    }
}

// ==================== single cooperative kernel ====================
// Pre-sync : xixj->lC + W transpose + bias preloads + adj pack (8-deep pipe)
// grid.sync
// Post-sync: R9's 7-barrier MLP chain (weight prefetch under intersect)
//
// Pack bit layout: task t: row r=t>>5, seg s=t&31. Lane l reads float4 at
// cols s*256+4l..4l+3; ballot(comp q) -> bits word t*4+q, bit l <-> col
// s*256+4l+q.
__global__ __launch_bounds__(1024, 1) void mono_kernel(
    const float* __restrict__ x,
    const float* __restrict__ adj,
    const int* __restrict__ tar,
    const float* __restrict__ W1c, const float* __restrict__ W2c,
    const float* __restrict__ W1j, const float* __restrict__ W2j,
    const float* __restrict__ Wl1, const float* __restrict__ Wl2,
    const float* __restrict__ b1c, const float* __restrict__ b2c,
    const float* __restrict__ b1j, const float* __restrict__ b2j,
    const float* __restrict__ bl1, const float* __restrict__ bl2,
    const float* __restrict__ Wout, const float* __restrict__ bout,
    unsigned short* __restrict__ Wt,
    unsigned long long* __restrict__ bits,
    float* __restrict__ out) {
  __shared__ unsigned short lA[TE][LDP];  // xcn -> h
  __shared__ unsigned short lB[TE][LDP];  // U2 -> h2
  __shared__ unsigned short lC[TE][LDP];  // xixj -> U1
  __shared__ int hits[TE][HCAP];
  __shared__ int nh[TE];
  __shared__ float sPart[16][TE];

  const int tid = threadIdx.x;
  const int lane = tid & 63;
  const int wave = tid >> 6;  // 0..15
  const int blk = blockIdx.x;
  const int e0 = blk * TE;

  // ---- per-lane constant preloads (overlap with everything below) ----
  const int lc = lane & 15;
  const int c0 = wave * 16 + lc;
  const float vb1c = b1c[c0];
  const float vb1j = b1j[c0];
  const float vb2 = b2c[c0] + b2j[c0];
  const float vbl1 = bl1[c0];
  const float vbl2 = bl2[c0];
  const float vwout = Wout[c0];
  const float vbout = bout[0];

  if (tid < TE) nh[tid] = 0;

  // ---- pre-sync (1): xixj -> lC ----
  {
    const int col = tid & 255;
    const int sub = tid >> 8;  // 0..3 -> 8 edges each
    float vi[8], vj[8];
#pragma unroll
    for (int p = 0; p < 8; ++p) {
      const int e = sub * 8 + p;
      vi[p] = x[(size_t)tar[e0 + e] * DIM + col];
      vj[p] = x[(size_t)tar[NE + e0 + e] * DIM + col];
    }
#pragma unroll
    for (int p = 0; p < 8; ++p)
      lC[sub * 8 + p][col] = f2bf(vi[p] * vj[p]);
  }

  // ---- pre-sync (2): weight transpose share ----
  // 6*65536 = 393216 elems over 262144 threads: <=2 each. Coalesced W read.
  {
    const int gid = blk * 1024 + tid;
#pragma unroll
    for (int r = 0; r < 2; ++r) {
      const int eid = gid + r * 262144;
      if (eid < 393216) {
        const int w = eid >> 16;
        const int rem = eid & 65535;   // = k*256 + n
        const int k = rem >> 8;
        const int n = rem & 255;
        const float* W = (w < 1) ? W1c : (w < 2) ? W2c : (w < 3) ? W1j
                       : (w < 4) ? W2j : (w < 5) ? Wl1 : Wl2;
        Wt[w * 65536 + n * DIM + k] = f2bf(W[rem]);
      }
    }
  }

  // ---- pre-sync (3): adj pack — 32 rows/block, 2 rows/wave, 8-deep pipe ----
  {
    const float4* __restrict__ adjv = (const float4*)adj;
    const int t0 = blk * 1024 + wave * 64;  // 64 float4-tasks per wave
    float4 buf[8];
#pragma unroll
    for (int k = 0; k < 8; ++k) {
      const int t = t0 + k;
      buf[k] = adjv[(size_t)(t >> 5) * 2048 + (t & 31) * 64 + lane];
    }
    for (int i = 0; i < 64; i += 8) {
#pragma unroll
      for (int k = 0; k < 8; ++k) {
        float4 v = buf[k];
        const int tn = t0 + ((i + k + 8) & 63);  // wrap tail (harmless reload)
        buf[k] = adjv[(size_t)(tn >> 5) * 2048 + (tn & 31) * 64 + lane];
        unsigned long long m0 = __ballot(v.x != 0.0f);
        unsigned long long m1 = __ballot(v.y != 0.0f);
        unsigned long long m2 = __ballot(v.z != 0.0f);
        unsigned long long m3 = __ballot(v.w != 0.0f);
        if (lane == 0) {
          const int t = t0 + i + k;
          unsigned long long* p = bits + (size_t)t * 4;
          p[0] = m0; p[1] = m1; p[2] = m2; p[3] = m3;
        }
      }
    }
  }

  cg::this_grid().sync();  // bits + Wt globally visible

  // ---- post-sync: weight prefetch first (latency hidden under intersect) ----
  bf16x8 wX[8], wY[8];
  load_w16(Wt + 2 * 65536, wX, lane, wave);  // W1j (used P3)
  load_w16(Wt + 0 * 65536, wY, lane, wave);  // W1c (used P4)

  // ---- bits words -> regs (32 thr/edge, 4 words each endpoint) ----
  const int e_a = tid >> 5;
  const int t32 = tid & 31;
  unsigned long long bw_i[4], bw_j[4];
  {
    const int ia = tar[e0 + e_a];
    const int ja = tar[NE + e0 + e_a];
    const unsigned long long* bi = bits + (size_t)ia * NW + t32 * 4;
    const unsigned long long* bj = bits + (size_t)ja * NW + t32 * 4;
#pragma unroll
    for (int q = 0; q < 4; ++q) { bw_i[q] = bi[q]; bw_j[q] = bj[q]; }
  }

  // ---- intersect (pure VALU + LDS atomics; weight loads in flight) ----
#pragma unroll
  for (int q = 0; q < 4; ++q) {
    unsigned long long m = bw_i[q] & bw_j[q];
    const int base = t32 << 8;
    while (m) {
      int b = __builtin_ctzll(m);
      m &= m - 1;
      int idx = atomicAdd(&nh[e_a], 1);
      if (idx < HCAP) hits[e_a][idx] = base + (b << 2) + q;  // node id
    }
  }
  __syncthreads();  // [2] hits ready

  f32x4 acc[2];
  const f32x4 z4 = {0.f, 0.f, 0.f, 0.f};

  // ---- P3: xcn gathers -> lA  ∥  U2 = relu(xixj @ W1j + b1j) -> lB ----
  {
    const int col = tid & 255;
    const int sub = tid >> 8;
    float xc[8];
#pragma unroll
    for (int p = 0; p < 8; ++p) {
      const int e = sub * 8 + p;
      const int n = nh[e] < HCAP ? nh[e] : HCAP;
      float s = 0.f;
      for (int h = 0; h < n; ++h)
        s += x[(size_t)hits[e][h] * DIM + col];
      xc[p] = s;
    }
    acc[0] = z4; acc[1] = z4;
    gemm16(lC, wX, acc, lane);                 // U2 (lC = xixj)
    load_w16(Wt + 1 * 65536, wX, lane, wave);  // reload wX = W2c
    epilogue16(acc, vb1j, true, lB, lane, wave);
#pragma unroll
    for (int p = 0; p < 8; ++p)
      lA[sub * 8 + p][col] = f2bf(xc[p]);
  }
  __syncthreads();  // [3] lA = xcn, lB = U2

  // ---- P4: U1 = relu(xcn @ W1c + b1c) -> lC ; reload wY = W2j ----
  acc[0] = z4; acc[1] = z4;
  gemm16(lA, wY, acc, lane);
  load_w16(Wt + 3 * 65536, wY, lane, wave);
  epilogue16(acc, vb1c, true, lC, lane, wave);
  __syncthreads();  // [4] lC = U1

  // ---- P5: h = U1@W2c + U2@W2j + b2 -> lA (no relu) ; wX=Wl1, wY=Wl2 ----
  acc[0] = z4; acc[1] = z4;
  gemm16(lC, wX, acc, lane);
  gemm16(lB, wY, acc, lane);
  load_w16(Wt + 4 * 65536, wX, lane, wave);  // Wl1
  load_w16(Wt + 5 * 65536, wY, lane, wave);  // Wl2
  epilogue16(acc, vb2, false, lA, lane, wave);
  __syncthreads();  // [5] lA = h

  // ---- P6: h2 = relu(h @ Wl1 + bl1) -> lB ----
  acc[0] = z4; acc[1] = z4;
  gemm16(lA, wX, acc, lane);
  epilogue16(acc, vbl1, true, lB, lane, wave);
  __syncthreads();  // [6] lB = h2

  // ---- P7: h3 = relu(h2 @ Wl2 + bl2) in regs ; GEMV partial reduce ----
  acc[0] = z4; acc[1] = z4;
  gemm16(lB, wY, acc, lane);
  {
    const int rg = (lane >> 4) * 4;
    float v[2][4];
#pragma unroll
    for (int m = 0; m < 2; ++m)
#pragma unroll
      for (int q = 0; q < 4; ++q) {
        float h3 = fmaxf(acc[m][q] + vbl2, 0.f);
        v[m][q] = h3 * vwout;
      }
#pragma unroll
    for (int o = 1; o < 16; o <<= 1)
#pragma unroll
      for (int m = 0; m < 2; ++m)
#pragma unroll
        for (int q = 0; q < 4; ++q)
          v[m][q] += __shfl_xor(v[m][q], o);
    if (lc == 0) {
#pragma unroll
      for (int m = 0; m < 2; ++m)
#pragma unroll
        for (int q = 0; q < 4; ++q)
          sPart[wave][m * 16 + rg + q] = v[m][q];
    }
  }
  __syncthreads();  // [7] sPart ready

  // ---- final: deterministic 16-way sum ----
  if (tid < TE) {
    float s = 0.f;
#pragma unroll
    for (int w = 0; w < 16; ++w) s += sPart[w][tid];
    out[e0 + tid] = s + vbout;
  }
}

extern "C" void kernel_launch(void* const* d_in, const int* in_sizes, int n_in,
                              void* d_out, int out_size, void* d_ws, size_t ws_size,
                              hipStream_t stream) {
  const float* x    = (const float*)d_in[0];
  const float* adj  = (const float*)d_in[1];
  const int*   tar  = (const int*)d_in[2];
  const float* W1c  = (const float*)d_in[3];
  const float* b1c  = (const float*)d_in[4];
  const float* W2c  = (const float*)d_in[5];
  const float* b2c  = (const float*)d_in[6];
  const float* W1j  = (const float*)d_in[7];
  const float* b1j  = (const float*)d_in[8];
  const float* W2j  = (const float*)d_in[9];
  const float* b2j  = (const float*)d_in[10];
  const float* Wl1  = (const float*)d_in[11];
  const float* bl1  = (const float*)d_in[12];
  const float* Wl2  = (const float*)d_in[13];
  const float* bl2  = (const float*)d_in[14];
  const float* Wout = (const float*)d_in[15];
  const float* bout = (const float*)d_in[16];

  char* ws = (char*)d_ws;
  unsigned short*     Wt   = (unsigned short*)(ws);                  // 768 KB
  unsigned long long* bits = (unsigned long long*)(ws + (1u << 20)); // 8 MB
  float* out = (float*)d_out;

  void* args[] = {
      (void*)&x, (void*)&adj, (void*)&tar,
      (void*)&W1c, (void*)&W2c, (void*)&W1j, (void*)&W2j,
      (void*)&Wl1, (void*)&Wl2,
      (void*)&b1c, (void*)&b2c, (void*)&b1j, (void*)&b2j,
      (void*)&bl1, (void*)&bl2, (void*)&Wout, (void*)&bout,
      (void*)&Wt, (void*)&bits, (void*)&out};

  hipLaunchCooperativeKernel((const void*)mono_kernel, dim3(NBLK), dim3(1024),
                             args, 0, stream);
}

// Round 11
// 81.640 us; speedup vs baseline: 1.6419x; 1.6419x over previous
//
#include <hip/hip_runtime.h>
#include <stdint.h>

#define NN 8192
#define NE 8192
#define DIM 256
#define NW 128   // 64-bit words per adjacency row (8192 bits)
#define HCAP 64  // max common neighbors; worst case i==j -> deg_max ~55
#define TE 32    // edges per block (fused)

typedef short bf16x8 __attribute__((ext_vector_type(8)));
typedef float f32x4 __attribute__((ext_vector_type(4)));

__device__ __forceinline__ unsigned short f2bf(float f) {
  uint32_t u = __builtin_bit_cast(uint32_t, f);
  u += 0x7fffu + ((u >> 16) & 1u);   // round-to-nearest-even
  return (unsigned short)(u >> 16);
}
__device__ __forceinline__ float bf2f(unsigned short h) {
  uint32_t u = ((uint32_t)h) << 16;
  return __builtin_bit_cast(float, u);
}
__device__ __forceinline__ uint32_t pack2bf(float a, float b) {
  return (uint32_t)f2bf(a) | ((uint32_t)f2bf(b) << 16);
}

// ============ prep: weight transpose (blocks 0..1535) + adj pack (rest) ====
// Pack bit layout: task t covers row r = t>>5, segment s = t&31 (256 cols).
// Lane l loads float4 at cols s*256 + 4l .. 4l+3. ballot(component q) ->
// word bits[r*128 + s*4 + q], bit l  <->  col = s*256 + 4*l + q.
__global__ __launch_bounds__(256) void prep_kernel(
    const float* __restrict__ adj,
    const float* __restrict__ W1c, const float* __restrict__ W2c,
    const float* __restrict__ W1j, const float* __restrict__ W2j,
    const float* __restrict__ Wl1, const float* __restrict__ Wl2,
    unsigned short* __restrict__ Wt,
    unsigned long long* __restrict__ bits) {
  const int blk = blockIdx.x;
  if (blk < 1536) {
    // Wt[w][n][k] = W[w][k][n]. Coalesced read (consecutive n = tid),
    // scattered 2B writes (stores don't stall).
    const float* Ws[6] = {W1c, W2c, W1j, W2j, Wl1, Wl2};
    const int w = blk >> 8;
    const int k = blk & 255;
    const int n = threadIdx.x;
    Wt[w * 65536 + n * DIM + k] = f2bf(Ws[w][k * DIM + n]);
  } else {
    const float4* __restrict__ adjv = (const float4*)adj;
    const int lane = threadIdx.x & 63;
    const int wv = (blk - 1536) * 4 + (threadIdx.x >> 6);
    const int nwv = 4096 * 4;
    const int total = NN * 32;  // float4-tasks
    // 8 tasks per iter (8 KB in flight per wave); t%8==0 -> all in one row,
    // 32 contiguous u64 words to store.
    for (int t = 8 * wv; t < total; t += 8 * nwv) {
      float4 v[8];
#pragma unroll
      for (int k = 0; k < 8; ++k)
        v[k] = adjv[(size_t)((t + k) >> 5) * 2048 + ((t + k) & 31) * 64 + lane];
      unsigned long long m[32];
#pragma unroll
      for (int k = 0; k < 8; ++k) {
        m[k * 4 + 0] = __ballot(v[k].x != 0.0f);
        m[k * 4 + 1] = __ballot(v[k].y != 0.0f);
        m[k * 4 + 2] = __ballot(v[k].z != 0.0f);
        m[k * 4 + 3] = __ballot(v[k].w != 0.0f);
      }
      if (lane == 0) {
        unsigned long long* p = bits + (size_t)(t >> 5) * NW + (t & 31) * 4;
#pragma unroll
        for (int q = 0; q < 32; ++q) p[q] = m[q];
      }
    }
  }
}

// ================= fused: 7-barrier pipeline ========
// Block: 1024 threads = 16 waves, TE=32 edges, 256 blocks (1/CU).
// Each wave owns 16 output cols (1 n-tile) x 2 m-tiles of 16 rows.
// A-frag: row = lane&15, k = (lane>>4)*8 + j
// B-frag: col = lane&15, k = (lane>>4)*8 + j  (register-resident, prefetched)
// C/D:    col = lane&15, row = (lane>>4)*4 + reg   (m89-verified)

#define LDP 264  // 256 + 8 bf16 pad (row stride 528 B, 2-way bank alias = free)

__device__ __forceinline__ void load_w16(const unsigned short* __restrict__ Wt,
                                         bf16x8 w[8], int lane, int wave) {
  const int lr = lane & 15;
  const int kl = (lane >> 4) * 8;
  const int n0 = wave * 16;
#pragma unroll
  for (int kk = 0; kk < 8; ++kk)
    w[kk] = *(const bf16x8*)(Wt + (size_t)(n0 + lr) * DIM + kk * 32 + kl);
}

__device__ __forceinline__ void gemm16(const unsigned short (*src)[LDP],
                                       const bf16x8 w[8],
                                       f32x4 acc[2], int lane) {
  const int lr = lane & 15;
  const int kl = (lane >> 4) * 8;
#pragma unroll
  for (int kk = 0; kk < 8; ++kk) {
    const int k0 = kk * 32 + kl;
    bf16x8 a0 = *(const bf16x8*)(&src[lr][k0]);
    bf16x8 a1 = *(const bf16x8*)(&src[16 + lr][k0]);
    acc[0] = __builtin_amdgcn_mfma_f32_16x16x32_bf16(a0, w[kk], acc[0], 0, 0, 0);
    acc[1] = __builtin_amdgcn_mfma_f32_16x16x32_bf16(a1, w[kk], acc[1], 0, 0, 0);
  }
}

__device__ __forceinline__ void epilogue16(f32x4 acc[2], float bb, bool relu,
                                           unsigned short (*dst)[LDP],
                                           int lane, int wave) {
  const int lc = lane & 15;
  const int rg = (lane >> 4) * 4;
  const int col = wave * 16 + lc;
#pragma unroll
  for (int m = 0; m < 2; ++m)
#pragma unroll
    for (int q = 0; q < 4; ++q) {
      float v = acc[m][q] + bb;
      if (relu) v = fmaxf(v, 0.f);
      dst[m * 16 + rg + q][col] = f2bf(v);
    }
}

__global__ __launch_bounds__(1024) void fused_kernel(
    const float* __restrict__ x,
    const unsigned long long* __restrict__ bits,
    const int* __restrict__ tar,
    const unsigned short* __restrict__ Wt,
    const float* __restrict__ b1c, const float* __restrict__ b2c,
    const float* __restrict__ b1j, const float* __restrict__ b2j,
    const float* __restrict__ bl1, const float* __restrict__ bl2,
    const float* __restrict__ Wout, const float* __restrict__ bout,
    float* __restrict__ out) {
  __shared__ unsigned short lA[TE][LDP];  // xcn -> h
  __shared__ unsigned short lB[TE][LDP];  // U2 -> h2
  __shared__ unsigned short lC[TE][LDP];  // xixj -> U1
  __shared__ int hits[TE][HCAP];
  __shared__ int nh[TE];
  __shared__ float sPart[16][TE];         // per-wave GEMV partials

  const int tid = threadIdx.x;
  const int lane = tid & 63;
  const int wave = tid >> 6;  // 0..15
  const int e0 = blockIdx.x * TE;
  const float4* __restrict__ x4 = (const float4*)x;

  // ---- per-lane constant preloads ----
  const int lc = lane & 15;
  const int c0 = wave * 16 + lc;
  const float vb1c = b1c[c0];
  const float vb1j = b1j[c0];
  const float vb2 = b2c[c0] + b2j[c0];
  const float vbl1 = bl1[c0];
  const float vbl2 = bl2[c0];
  const float vwout = Wout[c0];
  const float vbout = bout[0];

  if (tid < TE) nh[tid] = 0;

  // ---- (a) bits words -> regs (32 thr/edge, 4 words each endpoint) ----
  const int e_a = tid >> 5;
  const int t32 = tid & 31;
  unsigned long long bw_i[4], bw_j[4];
  {
    const int ia = tar[e0 + e_a];
    const int ja = tar[NE + e0 + e_a];
    const unsigned long long* bi = bits + (size_t)ia * NW + t32 * 4;
    const unsigned long long* bj = bits + (size_t)ja * NW + t32 * 4;
#pragma unroll
    for (int q = 0; q < 4; ++q) { bw_i[q] = bi[q]; bw_j[q] = bj[q]; }
  }

  // ---- (b) xixj -> lC, float4 path ; then issue W1j/W1c prefetch ----
  {
    const int c4 = tid & 63;   // float4-col
    const int g = tid >> 6;    // 0..15 -> edges g, g+16
#pragma unroll
    for (int p = 0; p < 2; ++p) {
      const int e = g + p * 16;
      float4 vi = x4[(size_t)tar[e0 + e] * 64 + c4];
      float4 vj = x4[(size_t)tar[NE + e0 + e] * 64 + c4];
      uint2 pk;
      pk.x = pack2bf(vi.x * vj.x, vi.y * vj.y);
      pk.y = pack2bf(vi.z * vj.z, vi.w * vj.w);
      *(uint2*)(&lC[e][c4 * 4]) = pk;
    }
  }
  bf16x8 wX[8], wY[8];
  load_w16(Wt + 2 * 65536, wX, lane, wave);  // W1j (used P3)
  load_w16(Wt + 0 * 65536, wY, lane, wave);  // W1c (used P4)
  __syncthreads();  // [1] nh zeroed; lC ready

  // ---- (c) intersect (pure VALU + LDS atomics; weight loads in flight) ----
#pragma unroll
  for (int q = 0; q < 4; ++q) {
    unsigned long long m = bw_i[q] & bw_j[q];
    const int base = t32 << 8;
    while (m) {
      int b = __builtin_ctzll(m);
      m &= m - 1;
      int idx = atomicAdd(&nh[e_a], 1);
      if (idx < HCAP) hits[e_a][idx] = base + (b << 2) + q;  // node id
    }
  }
  __syncthreads();  // [2] hits ready

  f32x4 acc[2];
  const f32x4 z4 = {0.f, 0.f, 0.f, 0.f};

  // ---- P3: xcn gathers (float4) -> lA  ∥  U2 = relu(xixj@W1j+b1j) -> lB ----
  {
    const int c4 = tid & 63;
    const int g = tid >> 6;
    float4 xc[2];
#pragma unroll
    for (int p = 0; p < 2; ++p) {
      const int e = g + p * 16;
      const int n = nh[e] < HCAP ? nh[e] : HCAP;
      float4 s = {0.f, 0.f, 0.f, 0.f};
      for (int h = 0; h < n; ++h) {
        float4 v = x4[(size_t)hits[e][h] * 64 + c4];
        s.x += v.x; s.y += v.y; s.z += v.z; s.w += v.w;
      }
      xc[p] = s;
    }
    acc[0] = z4; acc[1] = z4;
    gemm16(lC, wX, acc, lane);                 // U2 (lC = xixj)
    load_w16(Wt + 1 * 65536, wX, lane, wave);  // reload wX = W2c
    epilogue16(acc, vb1j, true, lB, lane, wave);
#pragma unroll
    for (int p = 0; p < 2; ++p) {
      const int e = g + p * 16;
      uint2 pk;
      pk.x = pack2bf(xc[p].x, xc[p].y);
      pk.y = pack2bf(xc[p].z, xc[p].w);
      *(uint2*)(&lA[e][c4 * 4]) = pk;
    }
  }
  __syncthreads();  // [3] lA = xcn, lB = U2

  // ---- P4: U1 = relu(xcn @ W1c + b1c) -> lC ; reload wY = W2j ----
  acc[0] = z4; acc[1] = z4;
  gemm16(lA, wY, acc, lane);
  load_w16(Wt + 3 * 65536, wY, lane, wave);
  epilogue16(acc, vb1c, true, lC, lane, wave);
  __syncthreads();  // [4] lC = U1

  // ---- P5: h = U1@W2c + U2@W2j + b2 -> lA (no relu) ; wX=Wl1, wY=Wl2 ----
  acc[0] = z4; acc[1] = z4;
  gemm16(lC, wX, acc, lane);
  gemm16(lB, wY, acc, lane);
  load_w16(Wt + 4 * 65536, wX, lane, wave);  // Wl1
  load_w16(Wt + 5 * 65536, wY, lane, wave);  // Wl2
  epilogue16(acc, vb2, false, lA, lane, wave);
  __syncthreads();  // [5] lA = h

  // ---- P6: h2 = relu(h @ Wl1 + bl1) -> lB ----
  acc[0] = z4; acc[1] = z4;
  gemm16(lA, wX, acc, lane);
  epilogue16(acc, vbl1, true, lB, lane, wave);
  __syncthreads();  // [6] lB = h2

  // ---- P7: h3 = relu(h2 @ Wl2 + bl2) in regs ; GEMV partial reduce ----
  acc[0] = z4; acc[1] = z4;
  gemm16(lB, wY, acc, lane);
  {
    const int rg = (lane >> 4) * 4;
    float v[2][4];
#pragma unroll
    for (int m = 0; m < 2; ++m)
#pragma unroll
      for (int q = 0; q < 4; ++q) {
        float h3 = fmaxf(acc[m][q] + vbl2, 0.f);
        v[m][q] = h3 * vwout;
      }
#pragma unroll
    for (int o = 1; o < 16; o <<= 1)
#pragma unroll
      for (int m = 0; m < 2; ++m)
#pragma unroll
        for (int q = 0; q < 4; ++q)
          v[m][q] += __shfl_xor(v[m][q], o);
    if (lc == 0) {
#pragma unroll
      for (int m = 0; m < 2; ++m)
#pragma unroll
        for (int q = 0; q < 4; ++q)
          sPart[wave][m * 16 + rg + q] = v[m][q];
    }
  }
  __syncthreads();  // [7] sPart ready

  // ---- final: deterministic 16-way sum ----
  if (tid < TE) {
    float s = 0.f;
#pragma unroll
    for (int w = 0; w < 16; ++w) s += sPart[w][tid];
    out[e0 + tid] = s + vbout;
  }
}

extern "C" void kernel_launch(void* const* d_in, const int* in_sizes, int n_in,
                              void* d_out, int out_size, void* d_ws, size_t ws_size,
                              hipStream_t stream) {
  const float* x    = (const float*)d_in[0];
  const float* adj  = (const float*)d_in[1];
  const int*   tar  = (const int*)d_in[2];
  const float* W1c  = (const float*)d_in[3];
  const float* b1c  = (const float*)d_in[4];
  const float* W2c  = (const float*)d_in[5];
  const float* b2c  = (const float*)d_in[6];
  const float* W1j  = (const float*)d_in[7];
  const float* b1j  = (const float*)d_in[8];
  const float* W2j  = (const float*)d_in[9];
  const float* b2j  = (const float*)d_in[10];
  const float* Wl1  = (const float*)d_in[11];
  const float* bl1  = (const float*)d_in[12];
  const float* Wl2  = (const float*)d_in[13];
  const float* bl2  = (const float*)d_in[14];
  const float* Wout = (const float*)d_in[15];
  const float* bout = (const float*)d_in[16];

  char* ws = (char*)d_ws;
  unsigned short*     Wt   = (unsigned short*)(ws);                  // 768 KB
  unsigned long long* bits = (unsigned long long*)(ws + (1u << 20)); // 8 MB

  prep_kernel<<<1536 + 4096, 256, 0, stream>>>(adj, W1c, W2c, W1j, W2j, Wl1,
                                               Wl2, Wt, bits);

  fused_kernel<<<NE / TE, 1024, 0, stream>>>(x, bits, tar, Wt, b1c, b2c, b1j,
                                             b2j, bl1, bl2, Wout, bout,
                                             (float*)d_out);
}